// Round 2
// 97.109 us; speedup vs baseline: 1.0361x; 1.0361x over previous
//
#include <hip/hip_runtime.h>

#define HDIM 128
#define BDIM 512

typedef __attribute__((ext_vector_type(8))) __bf16 bf16x8;
typedef __attribute__((ext_vector_type(4))) float  f32x4;

// ---------------- Kernel 1: P = F @ W via bf16 MFMA, K-split x4 waves/tile.
// grid: 512 blocks x 256 thr.
//  * K is a template parameter -> compile-time trip count -> full unroll ->
//    compiler pipelines the global loads instead of one latency chain/iter.
//  * bid swizzle groups the 8 ntile-blocks of one (net,mtile) onto the SAME
//    XCD (same bid%8): F rows are fetched once per L2 instead of 8x from HBM.
// Layouts (gfx950 16x16x32_bf16, HW-verified m89/m91/m120):
//   A[m][k]: m = lane&15, k = (lane>>4)*8 + j
//   B[k][n]: n = lane&15, k = (lane>>4)*8 + j
//   D[row][col]: col = lane&15, row = (lane>>4)*4 + reg
template<int K>
__device__ __forceinline__ f32x4 proj_acc(const float* __restrict__ F,
                                          const float* __restrict__ W,
                                          int m0, int n0, int wv, int l)
{
    constexpr int Ks = K >> 2;            // 512 or 192 (both %32==0)
    const int q = l >> 4, ln = l & 15;
    const float* Fp = &F[(size_t)(m0 + ln) * K + wv * Ks + q * 8];
    const float* Wp = &W[(size_t)(wv * Ks + q * 8) * HDIM + n0 + ln];
    f32x4 acc = {0.f, 0.f, 0.f, 0.f};
    #pragma unroll
    for (int k0 = 0; k0 < Ks; k0 += 32) {
        const float4 fa0 = *(const float4*)(Fp + k0);
        const float4 fa1 = *(const float4*)(Fp + k0 + 4);
        bf16x8 a, b;
        a[0] = (__bf16)fa0.x; a[1] = (__bf16)fa0.y; a[2] = (__bf16)fa0.z; a[3] = (__bf16)fa0.w;
        a[4] = (__bf16)fa1.x; a[5] = (__bf16)fa1.y; a[6] = (__bf16)fa1.z; a[7] = (__bf16)fa1.w;
        #pragma unroll
        for (int j = 0; j < 8; ++j)
            b[j] = (__bf16)Wp[(size_t)(k0 + j) * HDIM];
        acc = __builtin_amdgcn_mfma_f32_16x16x32_bf16(a, b, acc, 0, 0, 0);
    }
    return acc;
}

__global__ __launch_bounds__(256) void proj_mfma(
    const float* __restrict__ Ft, const float* __restrict__ Fs,
    const float* __restrict__ Wt, const float* __restrict__ Ws,
    __bf16* __restrict__ Pbt, __bf16* __restrict__ Pbs)
{
    const int tid = threadIdx.x;
    const int wv = tid >> 6, l = tid & 63;

    // XCD-grouping swizzle (bijective on 0..511): blocks sharing (net,mtile)
    // all get the same bid%8 -> same XCD under round-robin dispatch.
    const int bid = blockIdx.x;
    const int c  = bid & 7;               // XCD
    const int tt = bid >> 3;              // 0..63
    const int ntile = tt & 7;
    const int g  = ((tt >> 3) << 3) + c;  // mtile-group 0..63
    const int net = g >> 5, mtile = g & 31;

    const int m0 = mtile * 16, n0 = ntile * 16;

    f32x4 acc;
    __bf16* P;
    if (net == 0) { acc = proj_acc<2048>(Ft, Wt, m0, n0, wv, l); P = Pbt; }
    else          { acc = proj_acc<768 >(Fs, Ws, m0, n0, wv, l); P = Pbs; }

    __shared__ float lds[4 * 256];
    #pragma unroll
    for (int r = 0; r < 4; ++r) lds[wv * 256 + r * 64 + l] = acc[r];
    __syncthreads();

    // tid = r*64 + l2 position; sum 4 wave partials, store bf16.
    {
        const float s = lds[tid] + lds[256 + tid] + lds[512 + tid] + lds[768 + tid];
        const int r = tid >> 6, l2 = tid & 63;
        const int row = m0 + ((l2 >> 4) << 2) + r;
        const int col = n0 + (l2 & 15);
        P[(size_t)row * HDIM + col] = (__bf16)s;
    }
}

// ---------------- Kernel 2: U/V = Pb @ W1 (+ analytic bias term) via MFMA.
// grid: 1024 blocks x 64 thr. bid = net*512 + uvh*256 + mtile*8 + ntile.
// Bias fold: U[i,h] = (P@W1a)[i,h] + c[h],  c = b^T@W1a + b1 (row-independent).
__global__ __launch_bounds__(64) void uv_mfma(
    const __bf16* __restrict__ Pbt, const __bf16* __restrict__ Pbs,
    const float* __restrict__ bt, const float* __restrict__ bs,
    const float* __restrict__ W1, const float* __restrict__ b1,
    float* __restrict__ Ut, float* __restrict__ Vt,
    float* __restrict__ Us, float* __restrict__ Vs,
    float* __restrict__ out)
{
    const int t = blockIdx.x;
    const int net = t >> 9, uvh = (t >> 8) & 1;
    const int mtile = (t >> 3) & 31, ntile = t & 7;
    const int l = threadIdx.x;

    if (t == 0 && l == 0) out[0] = 0.f;   // zero atomic target for pair_kernel

    const __bf16* P   = net ? Pbs : Pbt;
    const float* bias = net ? bs : bt;
    float* O = net ? (uvh ? Vs : Us) : (uvh ? Vt : Ut);
    const float* W1o = W1 + (size_t)uvh * HDIM * HDIM;

    const int m0 = mtile * 16, n0 = ntile * 16;
    const int q = l >> 4, ln = l & 15;
    const int arow = m0 + ln, bn = n0 + ln;

    f32x4 acc = {0.f, 0.f, 0.f, 0.f};
    float cpart = 0.f;
    #pragma unroll
    for (int k0 = 0; k0 < HDIM; k0 += 32) {
        const int ka = k0 + q * 8;
        bf16x8 a = *(const bf16x8*)&P[(size_t)arow * HDIM + ka];
        bf16x8 b;
        #pragma unroll
        for (int j = 0; j < 8; ++j) {
            const float w = W1o[(size_t)(ka + j) * HDIM + bn];
            b[j] = (__bf16)w;
            cpart = fmaf(bias[ka + j], w, cpart);
        }
        acc = __builtin_amdgcn_mfma_f32_16x16x32_bf16(a, b, acc, 0, 0, 0);
    }
    cpart += __shfl_xor(cpart, 16, 64);
    cpart += __shfl_xor(cpart, 32, 64);
    const float cfull = cpart + (uvh == 0 ? b1[bn] : 0.f);

    #pragma unroll
    for (int r = 0; r < 4; ++r) {
        const int row = m0 + q * 4 + r;
        O[(size_t)row * HDIM + bn] = acc[r] + cfull;
    }
}

// ---------------- Kernel 3: pairwise relations.
// 512 threads/block (16x32), 2 pairs/thread/net -> 8 waves/block =
// 2 waves/SIMD for latency hiding. 32x32 output tile per block, LDS ~37 KB.
__global__ __launch_bounds__(512) void pair_kernel(
    const float* __restrict__ Ut, const float* __restrict__ Vt,
    const float* __restrict__ Us, const float* __restrict__ Vs,
    const float* __restrict__ W2, const float* __restrict__ b2,
    float* __restrict__ out)
{
    __shared__ alignas(16) float4 tUt[32 * 17];
    __shared__ alignas(16) float4 tVt[32 * 17];
    __shared__ alignas(16) float4 tUs[32 * 17];
    __shared__ alignas(16) float4 tVs[32 * 17];
    __shared__ alignas(16) float4 w2s[32];
    __shared__ float red[512];

    const int tx = threadIdx.x, ty = threadIdx.y;   // (16, 32)
    const int tid = ty * 16 + tx;
    const int i0 = blockIdx.y * 32, j0 = blockIdx.x * 32;

    const float4* Ut4 = (const float4*)Ut;
    const float4* Vt4 = (const float4*)Vt;
    const float4* Us4 = (const float4*)Us;
    const float4* Vs4 = (const float4*)Vs;

    if (tid < 32) w2s[tid] = ((const float4*)W2)[tid];

    float aT[2] = {0.f, 0.f};
    float aS[2] = {0.f, 0.f};

    for (int half = 0; half < 2; ++half) {
        const int c0 = half * 16;
        __syncthreads();
        {   // 512 threads stage 32 rows x 16 float4 per array, coalesced.
            const int r = tid >> 4, cc = tid & 15;
            tUt[r * 17 + cc] = Ut4[(size_t)(i0 + r) * 32 + c0 + cc];
            tVt[r * 17 + cc] = Vt4[(size_t)(j0 + r) * 32 + c0 + cc];
            tUs[r * 17 + cc] = Us4[(size_t)(i0 + r) * 32 + c0 + cc];
            tVs[r * 17 + cc] = Vs4[(size_t)(j0 + r) * 32 + c0 + cc];
        }
        __syncthreads();

        #pragma unroll 4
        for (int h4 = 0; h4 < 16; ++h4) {
            float4 w  = w2s[c0 + h4];
            float4 u  = tUt[ty * 17 + h4];          // row i = i0+ty (broadcast)
            float4 p  = tUs[ty * 17 + h4];
            float4 v0 = tVt[tx * 17 + h4];          // col j = j0+tx
            float4 v1 = tVt[(tx + 16) * 17 + h4];   // col j = j0+tx+16
            float4 q0 = tVs[tx * 17 + h4];
            float4 q1 = tVs[(tx + 16) * 17 + h4];

            aT[0] = fmaf(fmaxf(u.x + v0.x, 0.f), w.x,
                    fmaf(fmaxf(u.y + v0.y, 0.f), w.y,
                    fmaf(fmaxf(u.z + v0.z, 0.f), w.z,
                    fmaf(fmaxf(u.w + v0.w, 0.f), w.w, aT[0]))));
            aT[1] = fmaf(fmaxf(u.x + v1.x, 0.f), w.x,
                    fmaf(fmaxf(u.y + v1.y, 0.f), w.y,
                    fmaf(fmaxf(u.z + v1.z, 0.f), w.z,
                    fmaf(fmaxf(u.w + v1.w, 0.f), w.w, aT[1]))));
            aS[0] = fmaf(fmaxf(p.x + q0.x, 0.f), w.x,
                    fmaf(fmaxf(p.y + q0.y, 0.f), w.y,
                    fmaf(fmaxf(p.z + q0.z, 0.f), w.z,
                    fmaf(fmaxf(p.w + q0.w, 0.f), w.w, aS[0]))));
            aS[1] = fmaf(fmaxf(p.x + q1.x, 0.f), w.x,
                    fmaf(fmaxf(p.y + q1.y, 0.f), w.y,
                    fmaf(fmaxf(p.z + q1.z, 0.f), w.z,
                    fmaf(fmaxf(p.w + q1.w, 0.f), w.w, aS[1]))));
        }
    }

    const float b2v = b2[0];
    float local = 0.f;
    #pragma unroll
    for (int b = 0; b < 2; ++b) {
        const int i = i0 + ty;
        const int j = j0 + tx + 16 * b;
        if (i != j) {
            float tr = 1.f / (1.f + __expf(-(aT[b] + b2v)));
            float sr = 1.f / (1.f + __expf(-(aS[b] + b2v)));
            float d = sr - tr;
            local = fmaf(d, d, local);
        }
    }

    red[tid] = local;
    __syncthreads();
    #pragma unroll
    for (int s = 256; s > 0; s >>= 1) {
        if (tid < s) red[tid] += red[tid + s];
        __syncthreads();
    }
    if (tid == 0)
        atomicAdd(out, red[0] * (1.0f / ((float)BDIM * (float)BDIM)));
}

extern "C" void kernel_launch(void* const* d_in, const int* in_sizes, int n_in,
                              void* d_out, int out_size, void* d_ws, size_t ws_size,
                              hipStream_t stream) {
    const float* teacher = (const float*)d_in[0];   // [512,2048]
    const float* student = (const float*)d_in[1];   // [512,768]
    const float* Wt = (const float*)d_in[2];        // [2048,128]
    const float* bt = (const float*)d_in[3];        // [128]
    const float* Ws = (const float*)d_in[4];        // [768,128]
    const float* bs = (const float*)d_in[5];        // [128]
    const float* W1 = (const float*)d_in[6];        // [256,128]
    const float* b1 = (const float*)d_in[7];        // [128]
    const float* W2 = (const float*)d_in[8];        // [128,1]
    const float* b2 = (const float*)d_in[9];        // [1]
    float* out = (float*)d_out;

    const size_t M = (size_t)BDIM * HDIM;           // 65536 elements
    __bf16* Pbt = (__bf16*)d_ws;                    // [512][128] bf16
    __bf16* Pbs = Pbt + M;
    float* Ut = (float*)(Pbs + M);
    float* Vt = Ut + M;
    float* Us = Vt + M;
    float* Vs = Us + M;

    proj_mfma<<<512, 256, 0, stream>>>(teacher, student, Wt, Ws, Pbt, Pbs);

    uv_mfma<<<1024, 64, 0, stream>>>(Pbt, Pbs, bt, bs, W1, b1,
                                     Ut, Vt, Us, Vs, out);

    pair_kernel<<<dim3(16, 16), dim3(16, 32), 0, stream>>>(
        Ut, Vt, Us, Vs, W2, b2, out);
}